// Round 5
// baseline (177.413 us; speedup 1.0000x reference)
//
#include <hip/hip_runtime.h>
#include <stdint.h>

typedef float v4f __attribute__((ext_vector_type(4)));
typedef int v8i __attribute__((ext_vector_type(8)));

#define FP8_DENOM 358.4f  // FP8_MAX(448) * SCALE_MARGIN(0.8)

// ---------- helpers ----------

__device__ __forceinline__ unsigned pack4_fp8(float a, float b, float c, float d) {
  // v_cvt_pk_fp8_f32: RNE, saturating (values <=358.4 by construction)
  int v = 0;
  v = __builtin_amdgcn_cvt_pk_fp8_f32(a, b, v, false);  // bytes 0,1
  v = __builtin_amdgcn_cvt_pk_fp8_f32(c, d, v, true);   // bytes 2,3
  return (unsigned)v;
}

__device__ __forceinline__ void gload_lds16(const void* g, void* l) {
  // 16B-wide async global->LDS. LDS dest must be wave-uniform base + lane*16.
  __builtin_amdgcn_global_load_lds(
      (const __attribute__((address_space(1))) uint32_t*)(uintptr_t)g,
      (__attribute__((address_space(3))) uint32_t*)(uint32_t)(uintptr_t)l,
      16, 0, 0);
}

// ---------- stage 1: per-block partial amax (no atomics) ----------
// blocks 0..1023 cover x (4096 float4 each), blocks 1024..1279 cover w.

__global__ void __launch_bounds__(256) amax_part(const float4* __restrict__ x,
                                                 const float4* __restrict__ w,
                                                 float* __restrict__ part) {
  const int b = blockIdx.x, t = threadIdx.x;
  const float4* p = (b < 1024) ? x : w;
  const long base = (long)((b < 1024) ? b : (b - 1024)) * 4096;
  float m0 = 0.f, m1 = 0.f, m2 = 0.f, m3 = 0.f;
#pragma unroll
  for (int j = 0; j < 4; ++j) {
    float4 v0 = p[base + (j * 4 + 0) * 256 + t];
    float4 v1 = p[base + (j * 4 + 1) * 256 + t];
    float4 v2 = p[base + (j * 4 + 2) * 256 + t];
    float4 v3 = p[base + (j * 4 + 3) * 256 + t];
    m0 = fmaxf(m0, fmaxf(fmaxf(fabsf(v0.x), fabsf(v0.y)), fmaxf(fabsf(v0.z), fabsf(v0.w))));
    m1 = fmaxf(m1, fmaxf(fmaxf(fabsf(v1.x), fabsf(v1.y)), fmaxf(fabsf(v1.z), fabsf(v1.w))));
    m2 = fmaxf(m2, fmaxf(fmaxf(fabsf(v2.x), fabsf(v2.y)), fmaxf(fabsf(v2.z), fabsf(v2.w))));
    m3 = fmaxf(m3, fmaxf(fmaxf(fabsf(v3.x), fabsf(v3.y)), fmaxf(fabsf(v3.z), fabsf(v3.w))));
  }
  float m = fmaxf(fmaxf(m0, m1), fmaxf(m2, m3));
#pragma unroll
  for (int off = 32; off > 0; off >>= 1)
    m = fmaxf(m, __shfl_down(m, off, 64));
  __shared__ float red[4];
  const int lane = t & 63, wvid = t >> 6;
  if (lane == 0) red[wvid] = m;
  __syncthreads();
  if (t == 0) part[b] = fmaxf(fmaxf(red[0], red[1]), fmaxf(red[2], red[3]));
}

// ---------- stage 2: reduce partials; precompute scales & reciprocals ----------
// amax[0]=amax_x bits, [1]=amax_w, [2]=1/sx, [3]=1/sw, [4]=sx*sw

__global__ void __launch_bounds__(256) scale_reduce(const float* __restrict__ part,
                                                    unsigned* __restrict__ amax) {
  const int t = threadIdx.x;
  float mx = fmaxf(fmaxf(part[t], part[t + 256]), fmaxf(part[t + 512], part[t + 768]));
  float mw = part[1024 + t];
#pragma unroll
  for (int off = 32; off > 0; off >>= 1) {
    mx = fmaxf(mx, __shfl_down(mx, off, 64));
    mw = fmaxf(mw, __shfl_down(mw, off, 64));
  }
  __shared__ float rx[4], rw[4];
  const int lane = t & 63, wvid = t >> 6;
  if (lane == 0) { rx[wvid] = mx; rw[wvid] = mw; }
  __syncthreads();
  if (t == 0) {
    const float ax = fmaxf(fmaxf(rx[0], rx[1]), fmaxf(rx[2], rx[3]));
    const float aw = fmaxf(fmaxf(rw[0], rw[1]), fmaxf(rw[2], rw[3]));
    const float sx = ax / FP8_DENOM;
    const float sw = fmaxf(ax, aw) / FP8_DENOM;  // shared amax history max
    amax[0] = __float_as_uint(ax);
    amax[1] = __float_as_uint(aw);
    amax[2] = __float_as_uint(1.0f / sx);
    amax[3] = __float_as_uint(1.0f / sw);
    amax[4] = __float_as_uint(sx * sw);
  }
}

// ---------- quantize x and w -> fp8 e4m3fn codes ----------
// r4 bug: 64 B/thread read blocks -> 64-B lane stride -> 4x transaction
// amplification. Now lane-consecutive: thread t reads float4 [base+k*256+t]
// (1 KB/wave-instr coalesced), writes uint [base+k*256+t] (256 B/wave-instr).
// Exact fit: x = 4096 blocks * 1024 float4, w = 1024 blocks * 1024 float4.

__global__ void __launch_bounds__(256) quant_kernel(
    const float4* __restrict__ x, unsigned* __restrict__ xq,
    const float4* __restrict__ w, unsigned* __restrict__ wq,
    const unsigned* __restrict__ amax) {
  const int b = blockIdx.x, t = threadIdx.x;
  const int isw = (b >= 4096) ? 1 : 0;
  const float rs = __uint_as_float(amax[2 + isw]);  // 1/scale (uniform)
  const float4* in = isw ? w : x;
  unsigned* outq = isw ? wq : xq;
  const long base = (long)(isw ? (b - 4096) : b) * 1024;
  float4 v0 = in[base + 0 * 256 + t];
  float4 v1 = in[base + 1 * 256 + t];
  float4 v2 = in[base + 2 * 256 + t];
  float4 v3 = in[base + 3 * 256 + t];
  outq[base + 0 * 256 + t] = pack4_fp8(v0.x * rs, v0.y * rs, v0.z * rs, v0.w * rs);
  outq[base + 1 * 256 + t] = pack4_fp8(v1.x * rs, v1.y * rs, v1.z * rs, v1.w * rs);
  outq[base + 2 * 256 + t] = pack4_fp8(v2.x * rs, v2.y * rs, v2.z * rs, v2.w * rs);
  outq[base + 3 * 256 + t] = pack4_fp8(v3.x * rs, v3.y * rs, v3.z * rs, v3.w * rs);
}

// ---------- MX-scaled fp8 GEMM, 256x256 tile, double-buffered ----------
// r4 analysis: staging-BW bound (512 MB total tile traffic at 128^2 tiles;
// MfmaUtil 26% vs 14.7 us MFMA floor). 256x256 tile halves staging to 256 MB;
// with XCD = blockIdx.x%8 under linear dispatch, each XCD's 32 blocks share
// one 512 KB B-panel (L2-resident) and stream A once from L3.
// 512 threads = 8 waves (4x2); wave computes 64x128 via 4x8 16x16x128
// mfma_scale (unit e8m0 scales). b-frags loaded 4-at-a-time to hold VGPR<256.

__global__ void __launch_bounds__(512, 2) gemm_mx(
    const uint8_t* __restrict__ Aq, const uint8_t* __restrict__ Bq,
    const float* __restrict__ bias, float* __restrict__ out,
    const unsigned* __restrict__ amax) {
  constexpr int K = 2048, N = 2048, BK = 128, ITERS = K / BK;
  __shared__ alignas(16) uint8_t sA[2][256 * 128];  // 32 KB each
  __shared__ alignas(16) uint8_t sB[2][256 * 128];

  const int tid = threadIdx.x;
  const int lane = tid & 63;
  const int wid = tid >> 6;
  const int wy = wid >> 1, wx = wid & 1;  // 4x2 waves -> 64x128 per wave
  const long tileM = (long)blockIdx.y * 256;
  const long tileN = (long)blockIdx.x * 256;

  v4f acc[4][8];
#pragma unroll
  for (int i = 0; i < 4; ++i)
#pragma unroll
    for (int j = 0; j < 8; ++j) acc[i][j] = (v4f)(0.f);

  // staging: thread t -> rows srow + s*64 (s=0..3), phys chunk t&7,
  // source logical chunk = (t&7)^(srow&7) (row&7 invariant across s)
  const int srow = tid >> 3;
  const int schunk = (tid & 7) ^ (srow & 7);
  const uint8_t* gA = Aq + (tileM + srow) * K + schunk * 16;
  const uint8_t* gB = Bq + (tileN + srow) * K + schunk * 16;

  const int q = lane >> 4;     // k-block: lane holds k = q*32 .. q*32+31
  const int mrow = lane & 15;  // row within 16x16 tile

  // fragment LDS offsets (loop-invariant): logical chunks 2q,2q+1 of row r
  int aoff[4][2], boff[8][2];
#pragma unroll
  for (int i = 0; i < 4; ++i) {
    const int rA = wy * 64 + i * 16 + mrow, swA = rA & 7;
    aoff[i][0] = rA * 128 + 16 * ((2 * q) ^ swA);
    aoff[i][1] = rA * 128 + 16 * ((2 * q + 1) ^ swA);
  }
#pragma unroll
  for (int j = 0; j < 8; ++j) {
    const int rB = wx * 128 + j * 16 + mrow, swB = rB & 7;
    boff[j][0] = rB * 128 + 16 * ((2 * q) ^ swB);
    boff[j][1] = rB * 128 + 16 * ((2 * q + 1) ^ swB);
  }

  auto stage = [&](int buf, int k0) {
#pragma unroll
    for (int s = 0; s < 4; ++s)
      gload_lds16(gA + (long)s * 64 * K + k0, &sA[buf][s * 8192 + tid * 16]);
#pragma unroll
    for (int s = 0; s < 4; ++s)
      gload_lds16(gB + (long)s * 64 * K + k0, &sB[buf][s * 8192 + tid * 16]);
  };

  union Frag { v8i v; uint4 h[2]; };

  stage(0, 0);
  for (int it = 0; it < ITERS; ++it) {
    __syncthreads();  // drains staging(it) — overlapped with prev iter's MFMAs
    if (it + 1 < ITERS) stage((it + 1) & 1, (it + 1) * BK);  // async prefetch

    const uint8_t* bufA = sA[it & 1];
    const uint8_t* bufB = sB[it & 1];
    Frag a[4];
#pragma unroll
    for (int i = 0; i < 4; ++i) {
      a[i].h[0] = *(const uint4*)(bufA + aoff[i][0]);
      a[i].h[1] = *(const uint4*)(bufA + aoff[i][1]);
    }
#pragma unroll
    for (int jh = 0; jh < 2; ++jh) {
      Frag bfr[4];
#pragma unroll
      for (int jj = 0; jj < 4; ++jj) {
        bfr[jj].h[0] = *(const uint4*)(bufB + boff[jh * 4 + jj][0]);
        bfr[jj].h[1] = *(const uint4*)(bufB + boff[jh * 4 + jj][1]);
      }
#pragma unroll
      for (int i = 0; i < 4; ++i)
#pragma unroll
        for (int jj = 0; jj < 4; ++jj)
          acc[i][jh * 4 + jj] = __builtin_amdgcn_mfma_scale_f32_16x16x128_f8f6f4(
              a[i].v, bfr[jj].v, acc[i][jh * 4 + jj], /*cbsz=fp8*/ 0, /*blgp=fp8*/ 0,
              /*opsel_a*/ 0, 0x7F7F7F7F, /*opsel_b*/ 0, 0x7F7F7F7F);  // e8m0 127 = x1
    }
  }

  // epilogue: C/D layout col=lane&15, row=(lane>>4)*4+reg (shape-determined)
  const float scale = __uint_as_float(amax[4]);  // sx*sw precomputed
#pragma unroll
  for (int j = 0; j < 8; ++j) {
    const long col = tileN + wx * 128 + j * 16 + mrow;
    const float bv = bias[col];
#pragma unroll
    for (int i = 0; i < 4; ++i) {
      const long row = tileM + wy * 64 + i * 16 + q * 4;
#pragma unroll
      for (int r = 0; r < 4; ++r)
        out[(row + r) * N + col] = acc[i][j][r] * scale + bv;
    }
  }
}

// ---------- launch ----------

extern "C" void kernel_launch(void* const* d_in, const int* in_sizes, int n_in,
                              void* d_out, int out_size, void* d_ws, size_t ws_size,
                              hipStream_t stream) {
  const float* x = (const float*)d_in[0];     // [4,2048,2048] -> [8192,2048]
  const float* w = (const float*)d_in[1];     // [2048,2048]
  const float* bias = (const float*)d_in[2];  // [2048]
  float* out = (float*)d_out;                 // [8192,2048] fp32

  const int M = 8192, N = 2048, K = 2048;
  const long nx = (long)M * K, nw = (long)N * K;

  // ws layout: [0,32): amax/scale bits; [256,256+5120): 1280 float partials;
  // [8192, 8192+nx): xq codes; then wq codes. All 16B-aligned.
  unsigned* amax = (unsigned*)d_ws;
  float* part = (float*)((uint8_t*)d_ws + 256);
  uint8_t* xq = (uint8_t*)d_ws + 8192;
  uint8_t* wq = xq + nx;

  amax_part<<<1280, 256, 0, stream>>>((const float4*)x, (const float4*)w, part);
  scale_reduce<<<1, 256, 0, stream>>>(part, amax);
  quant_kernel<<<5120, 256, 0, stream>>>((const float4*)x, (unsigned*)xq,
                                         (const float4*)w, (unsigned*)wq, amax);
  gemm_mx<<<dim3(N / 256, M / 256), 512, 0, stream>>>(xq, wq, bias, out, amax);
}